// Round 2
// baseline (104686.401 us; speedup 1.0000x reference)
//
#include <hip/hip_runtime.h>
#include <hip/hip_cooperative_groups.h>

namespace cg = cooperative_groups;

// ---------------- constants ----------------
#define NB_SCAN   256
#define NT_SCAN   512
#define TDEC      600
#define ALIGN_OFF 1536000   // 16*1200*80

// ws layout (float offsets)
#define WS_ATT_H     0       // [2][16][512]
#define WS_ATT_C     16384   // [16][512]
#define WS_DEC_H     24576   // [2][16][512]
#define WS_DEC_C     40960   // [16][512]
#define WS_CTX       49152   // [2][16][512]
#define WS_CTXP      65536   // [2][16][512]
#define WS_MU        81920   // [2][16][8]
#define WS_STATE_END 82176
#define WS_DPART     90112   // [16][2048]
#define WS_PN        131072  // [600][16][256]

// ---------------- threefry-2x32 (JAX PRNG) ----------------
__host__ __device__ inline unsigned rotl_(unsigned x, int n){ return (x<<n)|(x>>(32-n)); }
__host__ __device__ inline void threefry2x32(unsigned k0, unsigned k1,
                                             unsigned x0, unsigned x1,
                                             unsigned &o0, unsigned &o1){
  unsigned ks[3] = {k0, k1, k0 ^ k1 ^ 0x1BD11BDAu};
  x0 += ks[0]; x1 += ks[1];
  const int R0[4] = {13,15,26,6};
  const int R1[4] = {17,29,16,24};
  #pragma unroll
  for (int i = 0; i < 5; ++i) {
    const int* R = (i & 1) ? R1 : R0;
    #pragma unroll
    for (int j = 0; j < 4; ++j) { x0 += x1; x1 = rotl_(x1, R[j]); x1 ^= x0; }
    x0 += ks[(i+1)%3];
    x1 += ks[(i+2)%3] + (unsigned)(i+1);
  }
  o0 = x0; o1 = x1;
}

// jax_threefry_partitionable=True (default since JAX 0.4.36):
// bits_i = o0 ^ o1 of threefry2x32(key, (hi32(i), lo32(i))); keep <=> u<0.5 <=> bit31==0
__device__ __forceinline__ bool keep_mask(unsigned i, unsigned k0, unsigned k1){
  unsigned o0, o1;
  threefry2x32(k0, k1, 0u, i, o0, o1);
  return (((o0 ^ o1) >> 31) == 0u);
}

// ---------------- math helpers ----------------
__device__ __forceinline__ float sigm_(float x){ return 1.f / (1.f + expf(-x)); }
__device__ __forceinline__ float softplus_(float x){ return log1pf(expf(-fabsf(x))) + fmaxf(x, 0.f); }

__device__ __forceinline__ void dot4(float& acc, const float* __restrict__ w,
                                     const float* __restrict__ x, int n){
  const float4* __restrict__ w4 = (const float4*)w;
  const float4* __restrict__ x4 = (const float4*)x;
  const int n4 = n >> 2;
  #pragma unroll 8
  for (int k = 0; k < n4; ++k) {
    float4 a = w4[k], v = x4[k];
    acc = fmaf(a.x, v.x, acc); acc = fmaf(a.y, v.y, acc);
    acc = fmaf(a.z, v.z, acc); acc = fmaf(a.w, v.w, acc);
  }
}

// ---------------- prenet (per-t blocks, all 16 b in-block) ----------------
__global__ __launch_bounds__(256) void prenet_kernel(
    const float* __restrict__ mel, const float* __restrict__ w1,
    const float* __restrict__ w2, float* __restrict__ ws,
    unsigned k1a, unsigned k1b, unsigned k2a, unsigned k2b)
{
  __shared__ float in_s[16][84];
  __shared__ float x1_s[16][260];
  const int t = blockIdx.x;         // 0..599
  const int tid = threadIdx.x;

  for (int i = tid; i < 16*80; i += 256) {
    int b = i / 80, c = i - b*80;
    float v = 0.f;
    if (t > 0) v = mel[((size_t)b*1200 + (2*t-1))*80 + c];
    in_s[b][c] = v;
  }
  __syncthreads();

  const int j2 = tid >> 4, b = tid & 15;

  // layer 1: 256 outputs, K=80, then threefry dropout (key dk1)
  for (int jo = 0; jo < 16; ++jo) {
    int j = jo*16 + j2;
    float acc = 0.f;
    dot4(acc, w1 + (size_t)j*80, &in_s[b][0], 80);
    acc = fmaxf(acc, 0.f);
    unsigned idx = ((unsigned)t*16u + (unsigned)b)*256u + (unsigned)j;
    acc = keep_mask(idx, k1a, k1b) ? acc*2.f : 0.f;
    x1_s[b][j] = acc;
  }
  __syncthreads();

  // layer 2: 256 outputs, K=256, dropout (key dk2), store to ws.pn
  for (int jo = 0; jo < 16; ++jo) {
    int j = jo*16 + j2;
    float acc = 0.f;
    dot4(acc, w2 + (size_t)j*256, &x1_s[b][0], 256);
    acc = fmaxf(acc, 0.f);
    unsigned idx = ((unsigned)t*16u + (unsigned)b)*256u + (unsigned)j;
    acc = keep_mask(idx, k2a, k2b) ? acc*2.f : 0.f;
    ws[WS_PN + ((size_t)t*16 + b)*256 + j] = acc;
  }
}

// ---------------- persistent scan kernel ----------------
struct ScanArgs {
  const float* memory; const float* memory_pitch; const int* mlen;
  const float* att_wih; const float* att_whh; const float* att_bih; const float* att_bhh;
  const float* q_w1; const float* q_b1; const float* q_w2; const float* q_b2;
  const float* dec_wih; const float* dec_whh; const float* dec_bih; const float* dec_bhh;
  const float* proj_w; const float* proj_b;
  float* out; float* ws;
};

__global__ __launch_bounds__(NT_SCAN) void scan_kernel(ScanArgs A)
{
  cg::grid_group grid = cg::this_grid();
  const int blk = blockIdx.x, tid = threadIdx.x;
  float* ws   = A.ws;
  float* attH = ws + WS_ATT_H;  float* attC = ws + WS_ATT_C;
  float* decH = ws + WS_DEC_H;  float* decC = ws + WS_DEC_C;
  float* ctxB = ws + WS_CTX;    float* ctpB = ws + WS_CTXP;
  float* muB  = ws + WS_MU;     float* dpart = ws + WS_DPART;
  const float* pn = ws + WS_PN;

  __shared__ union ShMem {
    struct { float red[32][16]; float gts[16][16]; } ab;   // att/dec/proj
    struct { float qred[256][2]; float q1[256]; float alpha[608];
             float q2[16]; float sc[20]; int iv[4]; } qa;  // q+alpha+ctx
  } sh;

  // zero-init all recurrent state
  for (int i = blk*NT_SCAN + tid; i < WS_STATE_END; i += NB_SCAN*NT_SCAN) ws[i] = 0.f;
  grid.sync();

  for (int t = 0; t <= TDEC; ++t) {
    const int pc = t & 1;          // parity of step t
    const int pp = (t + 1) & 1;    // parity of step t-1

    // ================= STAGE A : att(t)  ||  dec(t-1) =================
    if (blk < 128) {
      if (t < TDEC) {
        const int g = tid >> 4, b = tid & 15;
        const int rl = g >> 1, part = g & 1;
        const int gate = rl >> 2, ul = rl & 3;
        const int row = gate*512 + blk*4 + ul;
        const float* wih = A.att_wih + (size_t)row*768;
        const float* whh = A.att_whh + (size_t)row*512;
        const float* pnr = pn + ((size_t)t*16 + b)*256;
        const float* cx  = ctxB + pp*8192 + b*512;
        const float* hp  = attH + pp*8192 + b*512;
        float acc = 0.f;
        if (part == 0) {
          dot4(acc, wih,      pnr,    256);
          dot4(acc, wih+256,  cx,     384);
          acc += A.att_bih[row] + A.att_bhh[row];
        } else {
          dot4(acc, wih+640,  cx+384, 128);
          dot4(acc, whh,      hp,     512);
        }
        sh.ab.red[g][b] = acc;
        __syncthreads();
        if (tid < 256) {
          int rr = tid >> 4, bb = tid & 15;
          sh.ab.gts[rr][bb] = sh.ab.red[2*rr][bb] + sh.ab.red[2*rr+1][bb];
        }
        __syncthreads();
        if (tid < 64) {
          int u2 = tid >> 4, bb = tid & 15;
          float gi = sh.ab.gts[u2][bb],      gf = sh.ab.gts[4+u2][bb];
          float gg = sh.ab.gts[8+u2][bb],    go = sh.ab.gts[12+u2][bb];
          int u = blk*4 + u2;
          float c  = attC[bb*512 + u];
          float c2 = sigm_(gf)*c + sigm_(gi)*tanhf(gg);
          float h2 = sigm_(go)*tanhf(c2);
          attC[bb*512 + u] = c2;
          attH[pc*8192 + bb*512 + u] = h2;
        }
      }
    } else {
      if (t >= 1) {   // dec(t-1)
        const int g = tid >> 4, b = tid & 15;
        const int rl = g >> 1, part = g & 1;
        const int gate = rl >> 2, ul = rl & 3;
        const int row = gate*512 + (blk-128)*4 + ul;
        const float* wih = A.dec_wih + (size_t)row*1536;
        const float* whh = A.dec_whh + (size_t)row*512;
        const float* cx  = ctxB + pp*8192 + b*512;
        const float* cp  = ctpB + pp*8192 + b*512;
        const float* hp  = decH + pc*8192 + b*512;   // dec_h(t-2)
        float acc = 0.f;
        if (part == 0) {
          acc = dpart[b*2048 + row];                 // att_h part + biases
          dot4(acc, wih+512,  cx,     512);
          dot4(acc, wih+1024, cp,     256);
        } else {
          dot4(acc, wih+1280, cp+256, 256);
          dot4(acc, whh,      hp,     512);
        }
        sh.ab.red[g][b] = acc;
        __syncthreads();
        if (tid < 256) {
          int rr = tid >> 4, bb = tid & 15;
          sh.ab.gts[rr][bb] = sh.ab.red[2*rr][bb] + sh.ab.red[2*rr+1][bb];
        }
        __syncthreads();
        if (tid < 64) {
          int u2 = tid >> 4, bb = tid & 15;
          float gi = sh.ab.gts[u2][bb],      gf = sh.ab.gts[4+u2][bb];
          float gg = sh.ab.gts[8+u2][bb],    go = sh.ab.gts[12+u2][bb];
          int u = (blk-128)*4 + u2;
          float c  = decC[bb*512 + u];
          float c2 = sigm_(gf)*c + sigm_(gi)*tanhf(gg);
          float h2 = sigm_(go)*tanhf(c2);
          decC[bb*512 + u] = c2;
          decH[pp*8192 + bb*512 + u] = h2;           // dec_h(t-1)
        }
      }
    }
    grid.sync();

    // ====== STAGE B : q/alpha/ctx(t) || dec-partial(t) || proj(t-1) ======
    if (blk < 64) {
      if (t < TDEC) {
        const int b = blk >> 2, mat = (blk >> 1) & 1, dh = blk & 1;
        const float* hrow = attH + pc*8192 + b*512;
        { // q1 = tanh(att_h @ q_w1^T + b1), split-K 2
          int h2i = tid >> 1, part = tid & 1;
          float acc = 0.f;
          dot4(acc, A.q_w1 + (size_t)h2i*512 + part*256, hrow + part*256, 256);
          sh.qa.qred[h2i][part] = acc;
        }
        __syncthreads();
        if (tid < 256) sh.qa.q1[tid] = tanhf(sh.qa.qred[tid][0] + sh.qa.qred[tid][1] + A.q_b1[tid]);
        __syncthreads();
        if (tid < 15) {
          float acc = 0.f;
          dot4(acc, A.q_w2 + (size_t)tid*256, sh.qa.q1, 256);
          sh.qa.q2[tid] = acc + A.q_b2[tid];
        }
        __syncthreads();
        if (tid == 0) {
          float mx = -1e30f;
          for (int m = 0; m < 5; ++m) mx = fmaxf(mx, sh.qa.q2[m]);
          float s = 0.f, e[5];
          for (int m = 0; m < 5; ++m) { e[m] = expf(sh.qa.q2[m]-mx); s += e[m]; }
          float mn = 1e30f, mxu = -1e30f;
          for (int m = 0; m < 5; ++m) {
            float wv = e[m]/s + 1e-6f;
            float sg = softplus_(sh.qa.q2[5+m]) + 0.5f;
            float is = 1.f/sg;
            float dl = softplus_(sh.qa.q2[10+m]);
            float mu = muB[pp*128 + b*8 + m] + dl;
            sh.qa.sc[m] = wv; sh.qa.sc[5+m] = is; sh.qa.sc[10+m] = 0.5f*is; sh.qa.sc[15+m] = mu;
            mn = fminf(mn, mu); mxu = fmaxf(mxu, mu);
            if (mat == 0 && dh == 0) muB[pc*128 + b*8 + m] = mu;
          }
          int lo = (int)floorf(mn) - 56; if (lo < 0) lo = 0;
          int hi = (int)ceilf(mxu) + 57; if (hi > TDEC) hi = TDEC;
          sh.qa.iv[0] = lo; sh.qa.iv[1] = hi; sh.qa.iv[2] = A.mlen[b];
        }
        __syncthreads();
        const int lo = sh.qa.iv[0], hi = sh.qa.iv[1], len = sh.qa.iv[2];
        for (int te = tid; te < TDEC; te += NT_SCAN) {
          float a = 0.f;
          if (te >= lo && te < hi && te < len) {
            float jj = te + 0.5f;
            #pragma unroll
            for (int m = 0; m < 5; ++m) {
              float zc = (jj - sh.qa.sc[15+m]) * sh.qa.sc[5+m];
              float hh = sh.qa.sc[10+m];
              a += sh.qa.sc[m] * (sigm_(zc+hh) - sigm_(zc-hh));
            }
          }
          sh.qa.alpha[te] = a;
          if (mat == 0 && dh == 0)
            A.out[ALIGN_OFF + (size_t)b*360000 + (size_t)t*600 + te] = a;
        }
        __syncthreads();
        { // ctx over [lo,hi): 256 dims per block, te parity split
          int d = dh*256 + (tid >> 1), teh = tid & 1;
          const float* mem = mat ? A.memory_pitch : A.memory;
          float acc = 0.f;
          for (int te = lo + teh; te < hi; te += 2)
            acc = fmaf(sh.qa.alpha[te], mem[((size_t)b*600 + te)*512 + d], acc);
          sh.qa.qred[tid >> 1][teh] = acc;
          __syncthreads();
          if (tid < 256) {
            float v = sh.qa.qred[tid][0] + sh.qa.qred[tid][1];
            (mat ? ctpB : ctxB)[pc*8192 + b*512 + dh*256 + tid] = v;
          }
        }
      }
    } else if (blk < 128) {
      if (t < TDEC) {  // dec gate partial: att_h(t) part + biases
        int g = tid >> 4, b = tid & 15;
        int row = (blk-64)*32 + g;
        float acc = A.dec_bih[row] + A.dec_bhh[row];
        dot4(acc, A.dec_wih + (size_t)row*1536, attH + pc*8192 + b*512, 512);
        dpart[b*2048 + row] = acc;
      }
    } else if (blk < 144) {
      if (t >= 1) {    // proj(t-1) + mel write
        int pb = blk - 128;
        int g = tid >> 4, b = tid & 15;
        if (g < 30) {
          int rl = g/3, part = g - rl*3;
          int row = pb*10 + rl;
          const float* xin = (part == 0) ? decH + pp*8192 + b*512
                           : (part == 1) ? ctxB + pp*8192 + b*512
                                         : ctpB + pp*8192 + b*512;
          float acc = (part == 0) ? A.proj_b[row] : 0.f;
          dot4(acc, A.proj_w + (size_t)row*1536 + part*512, xin, 512);
          sh.ab.red[g][b] = acc;
        }
        __syncthreads();
        if (tid < 160) {
          int rl = tid >> 4, b2 = tid & 15;
          float v = sh.ab.red[rl*3][b2] + sh.ab.red[rl*3+1][b2] + sh.ab.red[rl*3+2][b2];
          int row = pb*10 + rl;
          A.out[(size_t)b2*96000 + (size_t)(t-1)*160 + row] = v;
        }
      }
    }
    grid.sync();
  }
}

// ---------------- host ----------------
extern "C" void kernel_launch(void* const* d_in, const int* in_sizes, int n_in,
                              void* d_out, int out_size, void* d_ws, size_t ws_size,
                              hipStream_t stream) {
  const float* memory = (const float*)d_in[0];
  const float* mel    = (const float*)d_in[1];
  const int*   mlen   = (const int*)  d_in[2];
  const float* memp   = (const float*)d_in[3];
  const float* pw1    = (const float*)d_in[4];
  const float* pw2    = (const float*)d_in[5];

  ScanArgs args;
  args.memory = memory; args.memory_pitch = memp; args.mlen = mlen;
  args.att_wih = (const float*)d_in[6];  args.att_whh = (const float*)d_in[7];
  args.att_bih = (const float*)d_in[8];  args.att_bhh = (const float*)d_in[9];
  args.q_w1    = (const float*)d_in[10]; args.q_b1    = (const float*)d_in[11];
  args.q_w2    = (const float*)d_in[12]; args.q_b2    = (const float*)d_in[13];
  args.dec_wih = (const float*)d_in[14]; args.dec_whh = (const float*)d_in[15];
  args.dec_bih = (const float*)d_in[16]; args.dec_bhh = (const float*)d_in[17];
  args.proj_w  = (const float*)d_in[18]; args.proj_b  = (const float*)d_in[19];
  args.out = (float*)d_out; args.ws = (float*)d_ws;

  // jax_threefry_partitionable=True split (foldlike):
  // subkey i = full threefry2x32 output of counter (0, i)
  unsigned dk1a, dk1b, dk2a, dk2b;
  threefry2x32(0u, 42u, 0u, 0u, dk1a, dk1b);   // dk1
  threefry2x32(0u, 42u, 0u, 1u, dk2a, dk2b);   // dk2

  prenet_kernel<<<dim3(600), dim3(256), 0, stream>>>(mel, pw1, pw2, (float*)d_ws,
                                                     dk1a, dk1b, dk2a, dk2b);

  void* kp[] = { &args };
  hipLaunchCooperativeKernel((void*)scan_kernel, dim3(NB_SCAN), dim3(NT_SCAN),
                             kp, 0, stream);
}

// Round 3
// 64047.797 us; speedup vs baseline: 1.6345x; 1.6345x over previous
//
#include <hip/hip_runtime.h>
#include <hip/hip_cooperative_groups.h>

namespace cg = cooperative_groups;

// ---------------- constants ----------------
#define NB_SCAN   256
#define NT_SCAN   512
#define TDEC      600
#define ALIGN_OFF 1536000   // 16*1200*80

// ws layout (float offsets)
#define WS_ATT_H     0       // [2][16][512]
#define WS_ATT_C     16384   // [16][512]
#define WS_DEC_H     24576   // [2][16][512]
#define WS_DEC_C     40960   // [16][512]
#define WS_CTX       49152   // [2][16][512]
#define WS_CTXP      65536   // [2][16][512]
#define WS_MU        81920   // [2][16][8]
#define WS_Q1        82176   // [16][256]
#define WS_QFLAG     86272   // [601][16] ints
#define WS_STATE_END 95888
#define WS_PN        131072  // [600][16][256]

// ---------------- threefry-2x32 (JAX PRNG, partitionable) ----------------
__host__ __device__ inline unsigned rotl_(unsigned x, int n){ return (x<<n)|(x>>(32-n)); }
__host__ __device__ inline void threefry2x32(unsigned k0, unsigned k1,
                                             unsigned x0, unsigned x1,
                                             unsigned &o0, unsigned &o1){
  unsigned ks[3] = {k0, k1, k0 ^ k1 ^ 0x1BD11BDAu};
  x0 += ks[0]; x1 += ks[1];
  const int R0[4] = {13,15,26,6};
  const int R1[4] = {17,29,16,24};
  #pragma unroll
  for (int i = 0; i < 5; ++i) {
    const int* R = (i & 1) ? R1 : R0;
    #pragma unroll
    for (int j = 0; j < 4; ++j) { x0 += x1; x1 = rotl_(x1, R[j]); x1 ^= x0; }
    x0 += ks[(i+1)%3];
    x1 += ks[(i+2)%3] + (unsigned)(i+1);
  }
  o0 = x0; o1 = x1;
}

__device__ __forceinline__ bool keep_mask(unsigned i, unsigned k0, unsigned k1){
  unsigned o0, o1;
  threefry2x32(k0, k1, 0u, i, o0, o1);
  return (((o0 ^ o1) >> 31) == 0u);
}

// ---------------- math helpers ----------------
__device__ __forceinline__ float sigm_(float x){ return 1.f / (1.f + expf(-x)); }
__device__ __forceinline__ float softplus_(float x){ return log1pf(expf(-fabsf(x))) + fmaxf(x, 0.f); }

__device__ __forceinline__ void dot4(float& acc, const float* __restrict__ w,
                                     const float* __restrict__ x, int n){
  const float4* __restrict__ w4 = (const float4*)w;
  const float4* __restrict__ x4 = (const float4*)x;
  const int n4 = n >> 2;
  #pragma unroll 8
  for (int k = 0; k < n4; ++k) {
    float4 a = w4[k], v = x4[k];
    acc = fmaf(a.x, v.x, acc); acc = fmaf(a.y, v.y, acc);
    acc = fmaf(a.z, v.z, acc); acc = fmaf(a.w, v.w, acc);
  }
}

// fully-unrolled in-wave distributed reduce: v[cnt*2] -> v[cnt], idx bit log2(h) ~ lane bit
#define RSTAGE(v, lane, h, cnt) { const bool hi_ = ((lane) & (h)) != 0;      \
  _Pragma("unroll") for (int i_ = 0; i_ < (cnt); ++i_) {                     \
    float s_ = hi_ ? (v)[i_] : (v)[i_+(cnt)];                                \
    float k_ = hi_ ? (v)[i_+(cnt)] : (v)[i_];                                \
    (v)[i_] = k_ + __shfl_xor(s_, (h), 64); } }

// ---------------- prenet (unchanged, validated) ----------------
__global__ __launch_bounds__(256) void prenet_kernel(
    const float* __restrict__ mel, const float* __restrict__ w1,
    const float* __restrict__ w2, float* __restrict__ ws,
    unsigned k1a, unsigned k1b, unsigned k2a, unsigned k2b)
{
  __shared__ float in_s[16][84];
  __shared__ float x1_s[16][260];
  const int t = blockIdx.x;
  const int tid = threadIdx.x;

  for (int i = tid; i < 16*80; i += 256) {
    int b = i / 80, c = i - b*80;
    float v = 0.f;
    if (t > 0) v = mel[((size_t)b*1200 + (2*t-1))*80 + c];
    in_s[b][c] = v;
  }
  __syncthreads();

  const int j2 = tid >> 4, b = tid & 15;

  for (int jo = 0; jo < 16; ++jo) {
    int j = jo*16 + j2;
    float acc = 0.f;
    dot4(acc, w1 + (size_t)j*80, &in_s[b][0], 80);
    acc = fmaxf(acc, 0.f);
    unsigned idx = ((unsigned)t*16u + (unsigned)b)*256u + (unsigned)j;
    acc = keep_mask(idx, k1a, k1b) ? acc*2.f : 0.f;
    x1_s[b][j] = acc;
  }
  __syncthreads();

  for (int jo = 0; jo < 16; ++jo) {
    int j = jo*16 + j2;
    float acc = 0.f;
    dot4(acc, w2 + (size_t)j*256, &x1_s[b][0], 256);
    acc = fmaxf(acc, 0.f);
    unsigned idx = ((unsigned)t*16u + (unsigned)b)*256u + (unsigned)j;
    acc = keep_mask(idx, k2a, k2b) ? acc*2.f : 0.f;
    ws[WS_PN + ((size_t)t*16 + b)*256 + j] = acc;
  }
}

// ---------------- persistent scan kernel ----------------
struct ScanArgs {
  const float* memory; const float* memory_pitch; const int* mlen;
  const float* att_wih; const float* att_whh; const float* att_bih; const float* att_bhh;
  const float* q_w1; const float* q_b1; const float* q_w2; const float* q_b2;
  const float* dec_wih; const float* dec_whh; const float* dec_bih; const float* dec_bhh;
  const float* proj_w; const float* proj_b;
  float* out; float* ws;
};

union ShMem {
  struct { float xs[8][1280]; } att;                       // 40 KB
  struct { float xs[4][2048]; float dbuf[4][64]; } dec;    // 33.8 KB
  struct { float ah[512]; float q1s[256]; float q2s[16];
           float sc[20]; float alpha[600]; int iv[4]; } q; // ~5.6 KB
};

// ======== ATT role: blocks 0..63, 8 units each, weights in regs ========
__device__ __forceinline__ void att_role(const ScanArgs& A, ShMem& sh,
                                         int blk, int tid, cg::grid_group& grid)
{
  float* ws = A.ws;
  float* attH = ws + WS_ATT_H; float* attC = ws + WS_ATT_C;
  float* ctxB = ws + WS_CTX;
  const float* pn = ws + WS_PN;
  const int lane = tid & 63, wv = tid >> 6;
  const int unit = blk*8 + wv;

  // weight regs: 4 gates x 5 chunks (k = c*256 + lane*4), Wcat=[wih(768)|whh(512)]
  float4 w4[4][5];
  #pragma unroll
  for (int gate = 0; gate < 4; ++gate) {
    int row = gate*512 + unit;
    #pragma unroll
    for (int c = 0; c < 5; ++c) {
      int k = c*256 + lane*4;
      const float* s = (k < 768) ? A.att_wih + (size_t)row*768 + k
                                 : A.att_whh + (size_t)row*512 + (k - 768);
      w4[gate][c] = *(const float4*)s;
    }
  }
  const int brow = (lane >> 4)*512 + unit;
  const float bias = A.att_bih[brow] + A.att_bhh[brow];

  grid.sync();
  for (int t = 0; t <= TDEC; ++t) {
    const int pc = t & 1, pp = (t + 1) & 1;
    if (t < TDEC) {
      float acc[64];
      #pragma unroll
      for (int i = 0; i < 64; ++i) acc[i] = 0.f;
      #pragma unroll
      for (int bc = 0; bc < 2; ++bc) {
        __syncthreads();
        // stage xs[8][1280] : x = [pn 256 | ctx 512 | attH 512], b = bc*8..+8
        for (int i = tid; i < 8*320; i += NT_SCAN) {
          int b8 = i / 320, k4 = i - b8*320, k = k4*4, b = bc*8 + b8;
          float4 v;
          if (k < 256)      v = *(const float4*)(pn + ((size_t)t*16 + b)*256 + k);
          else if (k < 768) v = *(const float4*)(ctxB + pp*8192 + b*512 + (k-256));
          else              v = *(const float4*)(attH + pp*8192 + b*512 + (k-768));
          *(float4*)&sh.att.xs[b8][k] = v;
        }
        __syncthreads();
        #pragma unroll
        for (int b8 = 0; b8 < 8; ++b8) {
          float4 x4[5];
          #pragma unroll
          for (int c = 0; c < 5; ++c) x4[c] = *(const float4*)&sh.att.xs[b8][c*256 + lane*4];
          #pragma unroll
          for (int gate = 0; gate < 4; ++gate) {
            float s = acc[gate*16 + bc*8 + b8];
            #pragma unroll
            for (int c = 0; c < 5; ++c) {
              s = fmaf(w4[gate][c].x, x4[c].x, s); s = fmaf(w4[gate][c].y, x4[c].y, s);
              s = fmaf(w4[gate][c].z, x4[c].z, s); s = fmaf(w4[gate][c].w, x4[c].w, s);
            }
            acc[gate*16 + bc*8 + b8] = s;
          }
        }
      }
      // reduce 64 vals across 64 lanes -> lane l holds (gate=l>>4, b=l&15)
      RSTAGE(acc, lane, 32, 32) RSTAGE(acc, lane, 16, 16) RSTAGE(acc, lane, 8, 8)
      RSTAGE(acc, lane, 4, 4)   RSTAGE(acc, lane, 2, 2)   RSTAGE(acc, lane, 1, 1)
      float g0 = acc[0] + bias;
      float gf = __shfl(g0, 16 + (lane & 15), 64);
      float gg = __shfl(g0, 32 + (lane & 15), 64);
      float go = __shfl(g0, 48 + (lane & 15), 64);
      if (lane < 16) {
        int b = lane;
        float c  = attC[b*512 + unit];
        float c2 = sigm_(gf)*c + sigm_(g0)*tanhf(gg);
        float h2 = sigm_(go)*tanhf(c2);
        attC[b*512 + unit] = c2;
        attH[pc*8192 + b*512 + unit] = h2;
      }
    }
    grid.sync();  // end S1
    grid.sync();  // end S2 (idle)
  }
}

// ======== DEC role: blocks 64..191, 4 units each, K split by wave pair ========
__device__ __forceinline__ void dec_role(const ScanArgs& A, ShMem& sh,
                                         int blk, int tid, cg::grid_group& grid)
{
  float* ws = A.ws;
  float* attH = ws + WS_ATT_H; float* decH = ws + WS_DEC_H; float* decC = ws + WS_DEC_C;
  float* ctxB = ws + WS_CTX;   float* ctpB = ws + WS_CTXP;
  const int lane = tid & 63, wv = tid >> 6;
  const int db = blk - 64;
  const int unit = db*4 + (wv & 3);
  const int half = wv >> 2, ul = wv & 3;

  // weights: 4 gates x 4 chunks, k = half*1024 + c*256 + lane*4, Wcat=[wih(1536)|whh(512)]
  float4 w4[4][4];
  #pragma unroll
  for (int gate = 0; gate < 4; ++gate) {
    int row = gate*512 + unit;
    #pragma unroll
    for (int c = 0; c < 4; ++c) {
      int k = half*1024 + c*256 + lane*4;
      const float* s = (k < 1536) ? A.dec_wih + (size_t)row*1536 + k
                                  : A.dec_whh + (size_t)row*512 + (k - 1536);
      w4[gate][c] = *(const float4*)s;
    }
  }
  const int brow = (lane >> 4)*512 + unit;
  const float bias = A.dec_bih[brow] + A.dec_bhh[brow];

  grid.sync();
  for (int t = 0; t <= TDEC; ++t) {
    const int pc = t & 1, pp = (t + 1) & 1;
    if (t >= 1) {   // dec(t-1): x = [attH(t-1), ctx(t-1), ctxp(t-1), decH(t-2)]
      float acc[64];
      #pragma unroll
      for (int i = 0; i < 64; ++i) acc[i] = 0.f;
      #pragma unroll
      for (int bc = 0; bc < 4; ++bc) {
        __syncthreads();
        for (int i = tid; i < 4*512; i += NT_SCAN) {
          int b4 = i >> 9, k4 = i & 511, k = k4*4, b = bc*4 + b4;
          float4 v;
          if (k < 512)       v = *(const float4*)(attH + pp*8192 + b*512 + k);
          else if (k < 1024) v = *(const float4*)(ctxB + pp*8192 + b*512 + (k-512));
          else if (k < 1536) v = *(const float4*)(ctpB + pp*8192 + b*512 + (k-1024));
          else               v = *(const float4*)(decH + pc*8192 + b*512 + (k-1536));
          *(float4*)&sh.dec.xs[b4][k] = v;
        }
        __syncthreads();
        #pragma unroll
        for (int b4 = 0; b4 < 4; ++b4) {
          float4 x4[4];
          #pragma unroll
          for (int c = 0; c < 4; ++c) x4[c] = *(const float4*)&sh.dec.xs[b4][half*1024 + c*256 + lane*4];
          #pragma unroll
          for (int gate = 0; gate < 4; ++gate) {
            float s = acc[gate*16 + bc*4 + b4];
            #pragma unroll
            for (int c = 0; c < 4; ++c) {
              s = fmaf(w4[gate][c].x, x4[c].x, s); s = fmaf(w4[gate][c].y, x4[c].y, s);
              s = fmaf(w4[gate][c].z, x4[c].z, s); s = fmaf(w4[gate][c].w, x4[c].w, s);
            }
            acc[gate*16 + bc*4 + b4] = s;
          }
        }
      }
      RSTAGE(acc, lane, 32, 32) RSTAGE(acc, lane, 16, 16) RSTAGE(acc, lane, 8, 8)
      RSTAGE(acc, lane, 4, 4)   RSTAGE(acc, lane, 2, 2)   RSTAGE(acc, lane, 1, 1)
      if (half == 1) sh.dec.dbuf[ul][lane] = acc[0];
      __syncthreads();
      float g0 = acc[0] + sh.dec.dbuf[ul][lane] + bias;   // valid on half==0
      float gf = __shfl(g0, 16 + (lane & 15), 64);
      float gg = __shfl(g0, 32 + (lane & 15), 64);
      float go = __shfl(g0, 48 + (lane & 15), 64);
      if (half == 0 && lane < 16) {
        int b = lane;
        float c  = decC[b*512 + unit];
        float c2 = sigm_(gf)*c + sigm_(g0)*tanhf(gg);
        float h2 = sigm_(go)*tanhf(c2);
        decC[b*512 + unit] = c2;
        decH[pp*8192 + b*512 + unit] = h2;   // dec_h(t-1)
      }
    }
    grid.sync();  // end S1
    grid.sync();  // end S2 (idle)
  }
}

// ======== Q role: blocks 192..223 = (b, half) pairs ========
__device__ __forceinline__ void q_role(const ScanArgs& A, ShMem& sh,
                                       int blk, int tid, cg::grid_group& grid)
{
  float* ws = A.ws;
  float* attH = ws + WS_ATT_H;
  float* ctxB = ws + WS_CTX; float* ctpB = ws + WS_CTXP;
  float* muB  = ws + WS_MU;
  float* q1buf = ws + WS_Q1;
  int* qflag = (int*)(ws + WS_QFLAG);
  const int qi = blk - 192, b = qi >> 1, half = qi & 1;
  const int mlen_b = A.mlen[b];

  grid.sync();
  for (int t = 0; t <= TDEC; ++t) {
    const int pc = t & 1, pp = (t + 1) & 1;
    grid.sync();  // end S1
    if (t < TDEC) {
      // stage attH(t)[b]
      sh.q.ah[tid] = attH[pc*8192 + b*512 + tid];
      __syncthreads();
      // q1 half: rows half*128 + tid>>2, kq = tid&3 (128-float slice)
      {
        const int row = half*128 + (tid >> 2), kq = tid & 3;
        const float4* wr = (const float4*)(A.q_w1 + (size_t)row*512 + kq*128);
        const float4* xr = (const float4*)&sh.q.ah[kq*128];
        float s = 0.f;
        #pragma unroll 8
        for (int j = 0; j < 32; ++j) {
          float4 a = wr[j], v = xr[j];
          s = fmaf(a.x, v.x, s); s = fmaf(a.y, v.y, s);
          s = fmaf(a.z, v.z, s); s = fmaf(a.w, v.w, s);
        }
        s += __shfl_xor(s, 1, 64);
        s += __shfl_xor(s, 2, 64);
        if (kq == 0) q1buf[b*256 + row] = s;
      }
      __threadfence();
      __syncthreads();
      if (tid == 0) {
        atomicAdd(&qflag[t*16 + b], 1);
        while (__hip_atomic_load(&qflag[t*16 + b], __ATOMIC_ACQUIRE,
                                 __HIP_MEMORY_SCOPE_AGENT) < 2)
          __builtin_amdgcn_s_sleep(1);
      }
      __syncthreads();
      if (tid < 256) sh.q.q1s[tid] = tanhf(q1buf[b*256 + tid] + A.q_b1[tid]);
      __syncthreads();
      if (tid < 240) {   // q2: 15 rows x 16 lanes x 16-float slice
        const int row = tid >> 4, l16 = tid & 15;
        const float4* wr = (const float4*)(A.q_w2 + (size_t)row*256 + l16*16);
        const float4* xr = (const float4*)&sh.q.q1s[l16*16];
        float s = 0.f;
        #pragma unroll
        for (int j = 0; j < 4; ++j) {
          float4 a = wr[j], v = xr[j];
          s = fmaf(a.x, v.x, s); s = fmaf(a.y, v.y, s);
          s = fmaf(a.z, v.z, s); s = fmaf(a.w, v.w, s);
        }
        s += __shfl_xor(s, 1, 64); s += __shfl_xor(s, 2, 64);
        s += __shfl_xor(s, 4, 64); s += __shfl_xor(s, 8, 64);
        if (l16 == 0) sh.q.q2s[row] = s + A.q_b2[row];
      }
      __syncthreads();
      if (tid == 0) {
        float mx = -1e30f;
        for (int m = 0; m < 5; ++m) mx = fmaxf(mx, sh.q.q2s[m]);
        float ssum = 0.f, e[5];
        for (int m = 0; m < 5; ++m) { e[m] = expf(sh.q.q2s[m]-mx); ssum += e[m]; }
        float mn = 1e30f, mxu = -1e30f;
        for (int m = 0; m < 5; ++m) {
          float wv2 = e[m]/ssum + 1e-6f;
          float sg  = softplus_(sh.q.q2s[5+m]) + 0.5f;
          float is  = 1.f/sg;
          float dl  = softplus_(sh.q.q2s[10+m]);
          float mu  = muB[pp*128 + b*8 + m] + dl;
          sh.q.sc[m] = wv2; sh.q.sc[5+m] = is; sh.q.sc[10+m] = 0.5f*is; sh.q.sc[15+m] = mu;
          mn = fminf(mn, mu); mxu = fmaxf(mxu, mu);
          if (half == 0) muB[pc*128 + b*8 + m] = mu;
        }
        int lo = (int)floorf(mn) - 56; if (lo < 0) lo = 0;
        int hi = (int)ceilf(mxu) + 57; if (hi > TDEC) hi = TDEC;
        sh.q.iv[0] = lo; sh.q.iv[1] = hi;
      }
      __syncthreads();
      const int lo = sh.q.iv[0], hi = sh.q.iv[1];
      for (int te = tid; te < TDEC; te += NT_SCAN) {
        float a = 0.f;
        if (te >= lo && te < hi && te < mlen_b) {
          float jj = te + 0.5f;
          #pragma unroll
          for (int m = 0; m < 5; ++m) {
            float zc = (jj - sh.q.sc[15+m]) * sh.q.sc[5+m];
            float hh = sh.q.sc[10+m];
            a += sh.q.sc[m] * (sigm_(zc+hh) - sigm_(zc-hh));
          }
        }
        sh.q.alpha[te] = a;
        if (half == 0)
          A.out[ALIGN_OFF + (size_t)b*360000 + (size_t)t*600 + te] = a;
      }
      __syncthreads();
      {  // ctx: this block's matrix, all 512 dims
        const float* mem = half ? A.memory_pitch : A.memory;
        float accv = 0.f;
        for (int te = lo; te < hi; ++te)
          accv = fmaf(sh.q.alpha[te], mem[((size_t)b*600 + te)*512 + tid], accv);
        (half ? ctpB : ctxB)[pc*8192 + b*512 + tid] = accv;
      }
      __syncthreads();
    }
    grid.sync();  // end S2
  }
}

// ======== PROJ role: blocks 224..239, 10 rows each ========
__device__ __forceinline__ void proj_role(const ScanArgs& A, ShMem& sh,
                                          int blk, int tid, cg::grid_group& grid)
{
  float* ws = A.ws;
  float* decH = ws + WS_DEC_H; float* ctxB = ws + WS_CTX; float* ctpB = ws + WS_CTXP;
  const int lane = tid & 63;
  const bool act = (tid < 320);
  const int row = (blk-224)*10 + (tid >> 5);
  const int l32 = tid & 31;

  float4 w4[12]; float pb = 0.f;
  if (act) {
    #pragma unroll
    for (int c = 0; c < 12; ++c)
      w4[c] = *(const float4*)(A.proj_w + (size_t)row*1536 + c*128 + l32*4);
    pb = A.proj_b[row];
  }

  grid.sync();
  for (int t = 0; t <= TDEC; ++t) {
    const int pp = (t + 1) & 1;
    grid.sync();  // end S1
    if (t >= 1 && act) {   // proj(t-1): x = [decH(t-1), ctx(t-1), ctxp(t-1)]
      float acc[16];
      #pragma unroll
      for (int i = 0; i < 16; ++i) acc[i] = 0.f;
      #pragma unroll
      for (int b = 0; b < 16; ++b) {
        #pragma unroll
        for (int c = 0; c < 12; ++c) {
          int k = c*128 + l32*4;
          const float* xp = (k < 512) ? decH + pp*8192 + b*512 + k
                          : (k < 1024) ? ctxB + pp*8192 + b*512 + (k-512)
                                       : ctpB + pp*8192 + b*512 + (k-1024);
          float4 v = *(const float4*)xp;
          float s = acc[b];
          s = fmaf(w4[c].x, v.x, s); s = fmaf(w4[c].y, v.y, s);
          s = fmaf(w4[c].z, v.z, s); s = fmaf(w4[c].w, v.w, s);
          acc[b] = s;
        }
      }
      // reduce 16 vals across the 32 lanes of this row-group
      #pragma unroll
      for (int i = 0; i < 16; ++i) acc[i] += __shfl_xor(acc[i], 16, 64);
      RSTAGE(acc, lane, 8, 8) RSTAGE(acc, lane, 4, 4)
      RSTAGE(acc, lane, 2, 2) RSTAGE(acc, lane, 1, 1)
      if ((lane & 31) < 16) {
        int b = lane & 15;
        A.out[(size_t)b*96000 + (size_t)(t-1)*160 + row] = acc[0] + pb;
      }
    }
    grid.sync();  // end S2
  }
}

__device__ __forceinline__ void idle_role(cg::grid_group& grid)
{
  grid.sync();
  for (int t = 0; t <= TDEC; ++t) { grid.sync(); grid.sync(); }
}

__global__ __launch_bounds__(NT_SCAN) void scan_kernel(ScanArgs A)
{
  cg::grid_group grid = cg::this_grid();
  const int blk = blockIdx.x, tid = threadIdx.x;
  __shared__ ShMem sh;

  // zero-init recurrent state + q1buf + flags
  for (int i = blk*NT_SCAN + tid; i < WS_STATE_END; i += NB_SCAN*NT_SCAN) A.ws[i] = 0.f;

  if (blk < 64)       att_role(A, sh, blk, tid, grid);
  else if (blk < 192) dec_role(A, sh, blk, tid, grid);
  else if (blk < 224) q_role(A, sh, blk, tid, grid);
  else if (blk < 240) proj_role(A, sh, blk, tid, grid);
  else                idle_role(grid);
}

// ---------------- host ----------------
extern "C" void kernel_launch(void* const* d_in, const int* in_sizes, int n_in,
                              void* d_out, int out_size, void* d_ws, size_t ws_size,
                              hipStream_t stream) {
  const float* memory = (const float*)d_in[0];
  const float* mel    = (const float*)d_in[1];
  const int*   mlen   = (const int*)  d_in[2];
  const float* memp   = (const float*)d_in[3];
  const float* pw1    = (const float*)d_in[4];
  const float* pw2    = (const float*)d_in[5];

  ScanArgs args;
  args.memory = memory; args.memory_pitch = memp; args.mlen = mlen;
  args.att_wih = (const float*)d_in[6];  args.att_whh = (const float*)d_in[7];
  args.att_bih = (const float*)d_in[8];  args.att_bhh = (const float*)d_in[9];
  args.q_w1    = (const float*)d_in[10]; args.q_b1    = (const float*)d_in[11];
  args.q_w2    = (const float*)d_in[12]; args.q_b2    = (const float*)d_in[13];
  args.dec_wih = (const float*)d_in[14]; args.dec_whh = (const float*)d_in[15];
  args.dec_bih = (const float*)d_in[16]; args.dec_bhh = (const float*)d_in[17];
  args.proj_w  = (const float*)d_in[18]; args.proj_b  = (const float*)d_in[19];
  args.out = (float*)d_out; args.ws = (float*)d_ws;

  // jax_threefry_partitionable split: subkey i = threefry(key, (0, i))
  unsigned dk1a, dk1b, dk2a, dk2b;
  threefry2x32(0u, 42u, 0u, 0u, dk1a, dk1b);
  threefry2x32(0u, 42u, 0u, 1u, dk2a, dk2b);

  prenet_kernel<<<dim3(600), dim3(256), 0, stream>>>(mel, pw1, pw2, (float*)d_ws,
                                                     dk1a, dk1b, dk2a, dk2b);

  void* kp[] = { &args };
  hipLaunchCooperativeKernel((void*)scan_kernel, dim3(NB_SCAN), dim3(NT_SCAN),
                             kp, 0, stream);
}

// Round 5
// 33160.477 us; speedup vs baseline: 3.1570x; 1.9314x over previous
//
#include <hip/hip_runtime.h>

// ---------------- constants ----------------
#define NB_SCAN   240
#define NT_SCAN   512
#define TDEC      600
#define ALIGN_OFF 1536000   // 16*1200*80

#define NGRP  16
#define GRPSZ 15

// ws layout (float offsets)
#define WS_ATT_H     0       // [2][16][512]
#define WS_ATT_C     16384   // [16][512]
#define WS_DEC_H     24576   // [2][16][512]
#define WS_DEC_C     40960   // [16][512]
#define WS_CTX       49152   // [2][16][512]
#define WS_CTXP      65536   // [2][16][512]
#define WS_STATE_END 82176
#define WS_PN        131072  // [600][16][256]

// ---------------- custom grid barrier ----------------
// All state in ONE struct so prenet (stream-ordered before scan) can zero it
// every launch -- bar state must NOT persist across launches (graph replays!).
struct BarSt {
  unsigned grp[NGRP][128];   // slot s at [g][s*32] (128B apart)
  unsigned root[128];        // slot s at [s*32]
  unsigned gen;              // monotonic within a launch; zeroed each launch
  unsigned pad[31];
};
__device__ BarSt barst;

__device__ __forceinline__ void bar_arrive(int g, unsigned k, int tid){
  __syncthreads();   // all block threads' work + stores drained
  if (tid == 0) {
    unsigned* gs = &barst.grp[g][(k & 3u)*32];
    unsigned r = __hip_atomic_fetch_add(gs, 1u, __ATOMIC_ACQ_REL, __HIP_MEMORY_SCOPE_AGENT);
    if (r == GRPSZ-1u) {
      __hip_atomic_store(gs, 0u, __ATOMIC_RELAXED, __HIP_MEMORY_SCOPE_AGENT);
      unsigned* rs = &barst.root[(k & 3u)*32];
      unsigned rr = __hip_atomic_fetch_add(rs, 1u, __ATOMIC_ACQ_REL, __HIP_MEMORY_SCOPE_AGENT);
      if (rr == NGRP-1u) {
        __hip_atomic_store(rs, 0u, __ATOMIC_RELAXED, __HIP_MEMORY_SCOPE_AGENT);
        __hip_atomic_store(&barst.gen, k + 1u, __ATOMIC_RELEASE, __HIP_MEMORY_SCOPE_AGENT);
      }
    }
  }
}

__device__ __forceinline__ void bar_wait(unsigned k, int tid){
  if (tid == 0) {
    const unsigned tgt = k + 1u;
    while ((int)(__hip_atomic_load(&barst.gen, __ATOMIC_RELAXED, __HIP_MEMORY_SCOPE_AGENT) - tgt) < 0)
      __builtin_amdgcn_s_sleep(1);
    (void)__hip_atomic_load(&barst.gen, __ATOMIC_ACQUIRE, __HIP_MEMORY_SCOPE_AGENT);
  }
  __syncthreads();
}

// ---------------- threefry-2x32 (JAX PRNG, partitionable) ----------------
__host__ __device__ inline unsigned rotl_(unsigned x, int n){ return (x<<n)|(x>>(32-n)); }
__host__ __device__ inline void threefry2x32(unsigned k0, unsigned k1,
                                             unsigned x0, unsigned x1,
                                             unsigned &o0, unsigned &o1){
  unsigned ks[3] = {k0, k1, k0 ^ k1 ^ 0x1BD11BDAu};
  x0 += ks[0]; x1 += ks[1];
  const int R0[4] = {13,15,26,6};
  const int R1[4] = {17,29,16,24};
  #pragma unroll
  for (int i = 0; i < 5; ++i) {
    const int* R = (i & 1) ? R1 : R0;
    #pragma unroll
    for (int j = 0; j < 4; ++j) { x0 += x1; x1 = rotl_(x1, R[j]); x1 ^= x0; }
    x0 += ks[(i+1)%3];
    x1 += ks[(i+2)%3] + (unsigned)(i+1);
  }
  o0 = x0; o1 = x1;
}

__device__ __forceinline__ bool keep_mask(unsigned i, unsigned k0, unsigned k1){
  unsigned o0, o1;
  threefry2x32(k0, k1, 0u, i, o0, o1);
  return (((o0 ^ o1) >> 31) == 0u);
}

// ---------------- math helpers ----------------
__device__ __forceinline__ float sigm_(float x){ return 1.f / (1.f + expf(-x)); }
__device__ __forceinline__ float softplus_(float x){ return log1pf(expf(-fabsf(x))) + fmaxf(x, 0.f); }

__device__ __forceinline__ void dot4(float& acc, const float* __restrict__ w,
                                     const float* __restrict__ x, int n){
  const float4* __restrict__ w4 = (const float4*)w;
  const float4* __restrict__ x4 = (const float4*)x;
  const int n4 = n >> 2;
  #pragma unroll 8
  for (int k = 0; k < n4; ++k) {
    float4 a = w4[k], v = x4[k];
    acc = fmaf(a.x, v.x, acc); acc = fmaf(a.y, v.y, acc);
    acc = fmaf(a.z, v.z, acc); acc = fmaf(a.w, v.w, acc);
  }
}

// fully-unrolled in-wave distributed reduce
#define RSTAGE(v, lane, h, cnt) { const bool hi_ = ((lane) & (h)) != 0;      \
  _Pragma("unroll") for (int i_ = 0; i_ < (cnt); ++i_) {                     \
    float s_ = hi_ ? (v)[i_] : (v)[i_+(cnt)];                                \
    float k_ = hi_ ? (v)[i_+(cnt)] : (v)[i_];                                \
    (v)[i_] = k_ + __shfl_xor(s_, (h), 64); } }

// ---------------- prenet (also zeroes barrier state every launch) ----------
__global__ __launch_bounds__(256) void prenet_kernel(
    const float* __restrict__ mel, const float* __restrict__ w1,
    const float* __restrict__ w2, float* __restrict__ ws,
    unsigned k1a, unsigned k1b, unsigned k2a, unsigned k2b)
{
  __shared__ float in_s[16][84];
  __shared__ float x1_s[16][260];
  const int t = blockIdx.x;
  const int tid = threadIdx.x;

  // reset grid-barrier state for the scan kernel (stream-ordered before it).
  // Critical for graph replay: bar state must not leak across launches.
  if (t == 0) {
    unsigned* p = (unsigned*)&barst;
    for (int i = tid; i < (int)(sizeof(BarSt)/4); i += 256) p[i] = 0u;
  }

  for (int i = tid; i < 16*80; i += 256) {
    int b = i / 80, c = i - b*80;
    float v = 0.f;
    if (t > 0) v = mel[((size_t)b*1200 + (2*t-1))*80 + c];
    in_s[b][c] = v;
  }
  __syncthreads();

  const int j2 = tid >> 4, b = tid & 15;

  for (int jo = 0; jo < 16; ++jo) {
    int j = jo*16 + j2;
    float acc = 0.f;
    dot4(acc, w1 + (size_t)j*80, &in_s[b][0], 80);
    acc = fmaxf(acc, 0.f);
    unsigned idx = ((unsigned)t*16u + (unsigned)b)*256u + (unsigned)j;
    acc = keep_mask(idx, k1a, k1b) ? acc*2.f : 0.f;
    x1_s[b][j] = acc;
  }
  __syncthreads();

  for (int jo = 0; jo < 16; ++jo) {
    int j = jo*16 + j2;
    float acc = 0.f;
    dot4(acc, w2 + (size_t)j*256, &x1_s[b][0], 256);
    acc = fmaxf(acc, 0.f);
    unsigned idx = ((unsigned)t*16u + (unsigned)b)*256u + (unsigned)j;
    acc = keep_mask(idx, k2a, k2b) ? acc*2.f : 0.f;
    ws[WS_PN + ((size_t)t*16 + b)*256 + j] = acc;
  }
}

// ---------------- persistent scan kernel ----------------
struct ScanArgs {
  const float* memory; const float* memory_pitch; const int* mlen;
  const float* att_wih; const float* att_whh; const float* att_bih; const float* att_bhh;
  const float* q_w1; const float* q_b1; const float* q_w2; const float* q_b2;
  const float* dec_wih; const float* dec_whh; const float* dec_bih; const float* dec_bhh;
  const float* proj_w; const float* proj_b;
  float* out; float* ws;
};

union ShMem {
  struct { float xs[8][1280]; } att;                       // 40 KB
  struct { float xs[4][2048]; float dbuf[4][64]; } dec;    // 33.8 KB
  struct { float ah[512]; float q1s[256]; float q2s[16];
           float sc[20]; float alpha[600]; float mun[8];
           int iv[4]; } q;                                 // ~5.6 KB
};

// ======== ATT role: blocks 0..63, 8 units each, weights in regs ========
__device__ __forceinline__ void att_role(const ScanArgs& A, ShMem& sh,
                                         int blk, int tid, int g)
{
  float* ws = A.ws;
  float* attH = ws + WS_ATT_H; float* attC = ws + WS_ATT_C;
  float* ctxB = ws + WS_CTX;
  const float* pn = ws + WS_PN;
  const int lane = tid & 63, wv = tid >> 6;
  const int unit = blk*8 + wv;

  float4 w4[4][5];
  #pragma unroll
  for (int gate = 0; gate < 4; ++gate) {
    int row = gate*512 + unit;
    #pragma unroll
    for (int c = 0; c < 5; ++c) {
      int k = c*256 + lane*4;
      const float* s = (k < 768) ? A.att_wih + (size_t)row*768 + k
                                 : A.att_whh + (size_t)row*512 + (k - 768);
      w4[gate][c] = *(const float4*)s;
    }
  }
  const int brow = (lane >> 4)*512 + unit;
  const float bias = A.att_bih[brow] + A.att_bhh[brow];

  unsigned k = 1;
  for (int t = 0; t <= TDEC; ++t, k += 2) {
    const int pc = t & 1, pp = (t + 1) & 1;
    if (t < TDEC) {
      float acc[64];
      #pragma unroll
      for (int i = 0; i < 64; ++i) acc[i] = 0.f;
      #pragma unroll
      for (int bc = 0; bc < 2; ++bc) {
        __syncthreads();
        for (int i = tid; i < 8*320; i += NT_SCAN) {
          int b8 = i / 320, k4 = i - b8*320, kk = k4*4, b = bc*8 + b8;
          float4 v;
          if (kk < 256)      v = *(const float4*)(pn + ((size_t)t*16 + b)*256 + kk);
          else if (kk < 768) v = *(const float4*)(ctxB + pp*8192 + b*512 + (kk-256));
          else               v = *(const float4*)(attH + pp*8192 + b*512 + (kk-768));
          *(float4*)&sh.att.xs[b8][kk] = v;
        }
        __syncthreads();
        #pragma unroll
        for (int b8 = 0; b8 < 8; ++b8) {
          float4 x4[5];
          #pragma unroll
          for (int c = 0; c < 5; ++c) x4[c] = *(const float4*)&sh.att.xs[b8][c*256 + lane*4];
          #pragma unroll
          for (int gate = 0; gate < 4; ++gate) {
            float s = acc[gate*16 + bc*8 + b8];
            #pragma unroll
            for (int c = 0; c < 5; ++c) {
              s = fmaf(w4[gate][c].x, x4[c].x, s); s = fmaf(w4[gate][c].y, x4[c].y, s);
              s = fmaf(w4[gate][c].z, x4[c].z, s); s = fmaf(w4[gate][c].w, x4[c].w, s);
            }
            acc[gate*16 + bc*8 + b8] = s;
          }
        }
      }
      RSTAGE(acc, lane, 32, 32) RSTAGE(acc, lane, 16, 16) RSTAGE(acc, lane, 8, 8)
      RSTAGE(acc, lane, 4, 4)   RSTAGE(acc, lane, 2, 2)   RSTAGE(acc, lane, 1, 1)
      float g0 = acc[0] + bias;
      float gf = __shfl(g0, 16 + (lane & 15), 64);
      float gg = __shfl(g0, 32 + (lane & 15), 64);
      float go = __shfl(g0, 48 + (lane & 15), 64);
      if (lane < 16) {
        int b = lane;
        float c  = attC[b*512 + unit];
        float c2 = sigm_(gf)*c + sigm_(g0)*tanhf(gg);
        float h2 = sigm_(go)*tanhf(c2);
        attC[b*512 + unit] = c2;
        attH[pc*8192 + b*512 + unit] = h2;
      }
    }
    bar_arrive(g, k, tid);       // S1-end signal
    bar_arrive(g, k+1, tid);     // S2-end signal (no S2 work)
    bar_wait(k+1, tid);          // need ctx(t) before S1(t+1)
  }
}

// ======== DEC role: blocks 64..191, 4 units each, K split by wave pair ========
__device__ __forceinline__ void dec_role(const ScanArgs& A, ShMem& sh,
                                         int blk, int tid, int g)
{
  float* ws = A.ws;
  float* attH = ws + WS_ATT_H; float* decH = ws + WS_DEC_H; float* decC = ws + WS_DEC_C;
  float* ctxB = ws + WS_CTX;   float* ctpB = ws + WS_CTXP;
  const int lane = tid & 63, wv = tid >> 6;
  const int db = blk - 64;
  const int unit = db*4 + (wv & 3);
  const int half = wv >> 2, ul = wv & 3;

  float4 w4[4][4];
  #pragma unroll
  for (int gate = 0; gate < 4; ++gate) {
    int row = gate*512 + unit;
    #pragma unroll
    for (int c = 0; c < 4; ++c) {
      int k = half*1024 + c*256 + lane*4;
      const float* s = (k < 1536) ? A.dec_wih + (size_t)row*1536 + k
                                  : A.dec_whh + (size_t)row*512 + (k - 1536);
      w4[gate][c] = *(const float4*)s;
    }
  }
  const int brow = (lane >> 4)*512 + unit;
  const float bias = A.dec_bih[brow] + A.dec_bhh[brow];

  unsigned k = 1;
  for (int t = 0; t <= TDEC; ++t, k += 2) {
    const int pc = t & 1, pp = (t + 1) & 1;
    if (t >= 1) {   // dec(t-1): x = [attH(t-1), ctx(t-1), ctxp(t-1), decH(t-2)]
      float acc[64];
      #pragma unroll
      for (int i = 0; i < 64; ++i) acc[i] = 0.f;
      #pragma unroll
      for (int bc = 0; bc < 4; ++bc) {
        __syncthreads();
        for (int i = tid; i < 4*512; i += NT_SCAN) {
          int b4 = i >> 9, k4 = i & 511, kk = k4*4, b = bc*4 + b4;
          float4 v;
          if (kk < 512)       v = *(const float4*)(attH + pp*8192 + b*512 + kk);
          else if (kk < 1024) v = *(const float4*)(ctxB + pp*8192 + b*512 + (kk-512));
          else if (kk < 1536) v = *(const float4*)(ctpB + pp*8192 + b*512 + (kk-1024));
          else                v = *(const float4*)(decH + pc*8192 + b*512 + (kk-1536));
          *(float4*)&sh.dec.xs[b4][kk] = v;
        }
        __syncthreads();
        #pragma unroll
        for (int b4 = 0; b4 < 4; ++b4) {
          float4 x4[4];
          #pragma unroll
          for (int c = 0; c < 4; ++c) x4[c] = *(const float4*)&sh.dec.xs[b4][half*1024 + c*256 + lane*4];
          #pragma unroll
          for (int gate = 0; gate < 4; ++gate) {
            float s = acc[gate*16 + bc*4 + b4];
            #pragma unroll
            for (int c = 0; c < 4; ++c) {
              s = fmaf(w4[gate][c].x, x4[c].x, s); s = fmaf(w4[gate][c].y, x4[c].y, s);
              s = fmaf(w4[gate][c].z, x4[c].z, s); s = fmaf(w4[gate][c].w, x4[c].w, s);
            }
            acc[gate*16 + bc*4 + b4] = s;
          }
        }
      }
      RSTAGE(acc, lane, 32, 32) RSTAGE(acc, lane, 16, 16) RSTAGE(acc, lane, 8, 8)
      RSTAGE(acc, lane, 4, 4)   RSTAGE(acc, lane, 2, 2)   RSTAGE(acc, lane, 1, 1)
      if (half == 1) sh.dec.dbuf[ul][lane] = acc[0];
      __syncthreads();
      float g0 = acc[0] + sh.dec.dbuf[ul][lane] + bias;   // valid on half==0
      float gf = __shfl(g0, 16 + (lane & 15), 64);
      float gg = __shfl(g0, 32 + (lane & 15), 64);
      float go = __shfl(g0, 48 + (lane & 15), 64);
      if (half == 0 && lane < 16) {
        int b = lane;
        float c  = decC[b*512 + unit];
        float c2 = sigm_(gf)*c + sigm_(g0)*tanhf(gg);
        float h2 = sigm_(go)*tanhf(c2);
        decC[b*512 + unit] = c2;
        decH[pp*8192 + b*512 + unit] = h2;   // dec_h(t-1)
      }
    }
    bar_arrive(g, k, tid);
    bar_arrive(g, k+1, tid);
    bar_wait(k+1, tid);
  }
}

// ======== Q role: blocks 192..223 = (b, half), fully self-contained ========
__device__ __forceinline__ void q_role(const ScanArgs& A, ShMem& sh,
                                       int blk, int tid, int g)
{
  float* ws = A.ws;
  float* attH = ws + WS_ATT_H;
  float* ctxB = ws + WS_CTX; float* ctpB = ws + WS_CTXP;
  const int qi = blk - 192, b = qi >> 1, half = qi & 1;
  const int mlen_b = A.mlen[b];

  if (tid < 8) sh.q.mun[tid] = 0.f;   // private mu state (identical in both halves)

  unsigned k = 1;
  for (int t = 0; t <= TDEC; ++t, k += 2) {
    const int pc = t & 1;
    bar_arrive(g, k, tid);   // S1-end signal
    bar_wait(k, tid);        // need attH(t)
    if (t < TDEC) {
      sh.q.ah[tid] = attH[pc*8192 + b*512 + tid];
      __syncthreads();
      { // q1: all 256 rows, row = tid>>1, kq = tid&1 (256-float slice)
        const int row = tid >> 1, kq = tid & 1;
        const float4* wr = (const float4*)(A.q_w1 + (size_t)row*512 + kq*256);
        const float4* xr = (const float4*)&sh.q.ah[kq*256];
        float s0 = 0.f, s1 = 0.f;
        #pragma unroll 8
        for (int j = 0; j < 32; ++j) {
          float4 a = wr[2*j],   v = xr[2*j];
          s0 = fmaf(a.x, v.x, s0); s0 = fmaf(a.y, v.y, s0);
          s0 = fmaf(a.z, v.z, s0); s0 = fmaf(a.w, v.w, s0);
          float4 a2 = wr[2*j+1], v2 = xr[2*j+1];
          s1 = fmaf(a2.x, v2.x, s1); s1 = fmaf(a2.y, v2.y, s1);
          s1 = fmaf(a2.z, v2.z, s1); s1 = fmaf(a2.w, v2.w, s1);
        }
        float s = s0 + s1;
        s += __shfl_xor(s, 1, 64);
        if (kq == 0) sh.q.q1s[row] = tanhf(s + A.q_b1[row]);
      }
      __syncthreads();
      if (tid < 240) {   // q2: 15 rows x 16 lanes x 16-float slice
        const int row = tid >> 4, l16 = tid & 15;
        const float4* wr = (const float4*)(A.q_w2 + (size_t)row*256 + l16*16);
        const float4* xr = (const float4*)&sh.q.q1s[l16*16];
        float s = 0.f;
        #pragma unroll
        for (int j = 0; j < 4; ++j) {
          float4 a = wr[j], v = xr[j];
          s = fmaf(a.x, v.x, s); s = fmaf(a.y, v.y, s);
          s = fmaf(a.z, v.z, s); s = fmaf(a.w, v.w, s);
        }
        s += __shfl_xor(s, 1, 64); s += __shfl_xor(s, 2, 64);
        s += __shfl_xor(s, 4, 64); s += __shfl_xor(s, 8, 64);
        if (l16 == 0) sh.q.q2s[row] = s + A.q_b2[row];
      }
      __syncthreads();
      if (tid == 0) {
        float mx = -1e30f;
        for (int m = 0; m < 5; ++m) mx = fmaxf(mx, sh.q.q2s[m]);
        float ssum = 0.f, e[5];
        for (int m = 0; m < 5; ++m) { e[m] = expf(sh.q.q2s[m]-mx); ssum += e[m]; }
        float mn = 1e30f, mxu = -1e30f;
        for (int m = 0; m < 5; ++m) {
          float wv2 = e[m]/ssum + 1e-6f;
          float sg  = softplus_(sh.q.q2s[5+m]) + 0.5f;
          float is  = 1.f/sg;
          float dl  = softplus_(sh.q.q2s[10+m]);
          float mu  = sh.q.mun[m] + dl;
          sh.q.sc[m] = wv2; sh.q.sc[5+m] = is; sh.q.sc[10+m] = 0.5f*is; sh.q.sc[15+m] = mu;
          sh.q.mun[m] = mu;
          mn = fminf(mn, mu); mxu = fmaxf(mxu, mu);
        }
        int lo = (int)floorf(mn) - 56; if (lo < 0) lo = 0;
        int hi = (int)ceilf(mxu) + 57; if (hi > TDEC) hi = TDEC;
        sh.q.iv[0] = lo; sh.q.iv[1] = hi;
      }
      __syncthreads();
      const int lo = sh.q.iv[0], hi = sh.q.iv[1];
      for (int te = tid; te < TDEC; te += NT_SCAN) {
        float a = 0.f;
        if (te >= lo && te < hi && te < mlen_b) {
          float jj = te + 0.5f;
          #pragma unroll
          for (int m = 0; m < 5; ++m) {
            float zc = (jj - sh.q.sc[15+m]) * sh.q.sc[5+m];
            float hh = sh.q.sc[10+m];
            a += sh.q.sc[m] * (sigm_(zc+hh) - sigm_(zc-hh));
          }
        }
        sh.q.alpha[te] = a;
        if (half == 0)
          A.out[ALIGN_OFF + (size_t)b*360000 + (size_t)t*600 + te] = a;
      }
      __syncthreads();
      {  // ctx: this block's matrix, all 512 dims, 4-way acc split
        const float* mem = half ? A.memory_pitch : A.memory;
        float a0=0.f, a1=0.f, a2=0.f, a3=0.f;
        int te = lo;
        for (; te + 3 < hi; te += 4) {
          const float* mp = mem + ((size_t)b*600 + te)*512 + tid;
          a0 = fmaf(sh.q.alpha[te],   mp[0],    a0);
          a1 = fmaf(sh.q.alpha[te+1], mp[512],  a1);
          a2 = fmaf(sh.q.alpha[te+2], mp[1024], a2);
          a3 = fmaf(sh.q.alpha[te+3], mp[1536], a3);
        }
        for (; te < hi; ++te)
          a0 = fmaf(sh.q.alpha[te], mem[((size_t)b*600 + te)*512 + tid], a0);
        (half ? ctpB : ctxB)[pc*8192 + b*512 + tid] = (a0+a1)+(a2+a3);
      }
    }
    bar_arrive(g, k+1, tid);   // S2-end signal; no wait (next dep is S1-end(t+1))
  }
}

// ======== PROJ role: blocks 224..239, 10 rows each ========
__device__ __forceinline__ void proj_role(const ScanArgs& A, ShMem& sh,
                                          int blk, int tid, int g)
{
  float* ws = A.ws;
  float* decH = ws + WS_DEC_H; float* ctxB = ws + WS_CTX; float* ctpB = ws + WS_CTXP;
  const int lane = tid & 63;
  const bool act = (tid < 320);
  const int row = (blk-224)*10 + (tid >> 5);
  const int l32 = tid & 31;

  float4 w4[12]; float pb = 0.f;
  if (act) {
    #pragma unroll
    for (int c = 0; c < 12; ++c)
      w4[c] = *(const float4*)(A.proj_w + (size_t)row*1536 + c*128 + l32*4);
    pb = A.proj_b[row];
  }

  unsigned k = 1;
  for (int t = 0; t <= TDEC; ++t, k += 2) {
    const int pp = (t + 1) & 1;
    bar_arrive(g, k, tid);   // S1-end signal
    bar_wait(k, tid);        // need decH(t-1)
    if (t >= 1 && act) {     // proj(t-1): x = [decH(t-1), ctx(t-1), ctxp(t-1)]
      float acc[16];
      #pragma unroll
      for (int i = 0; i < 16; ++i) acc[i] = 0.f;
      #pragma unroll
      for (int b = 0; b < 16; ++b) {
        #pragma unroll
        for (int c = 0; c < 12; ++c) {
          int kk = c*128 + l32*4;
          const float* xp = (kk < 512) ? decH + pp*8192 + b*512 + kk
                          : (kk < 1024) ? ctxB + pp*8192 + b*512 + (kk-512)
                                        : ctpB + pp*8192 + b*512 + (kk-1024);
          float4 v = *(const float4*)xp;
          float s = acc[b];
          s = fmaf(w4[c].x, v.x, s); s = fmaf(w4[c].y, v.y, s);
          s = fmaf(w4[c].z, v.z, s); s = fmaf(w4[c].w, v.w, s);
          acc[b] = s;
        }
      }
      #pragma unroll
      for (int i = 0; i < 16; ++i) acc[i] += __shfl_xor(acc[i], 16, 64);
      RSTAGE(acc, lane, 8, 8) RSTAGE(acc, lane, 4, 4)
      RSTAGE(acc, lane, 2, 2) RSTAGE(acc, lane, 1, 1)
      if ((lane & 31) < 16) {
        int b = lane & 15;
        A.out[(size_t)b*96000 + (size_t)(t-1)*160 + row] = acc[0] + pb;
      }
    }
    bar_arrive(g, k+1, tid);   // S2-end signal; no wait
  }
}

__global__ __launch_bounds__(NT_SCAN) void scan_kernel(ScanArgs A)
{
  const int blk = blockIdx.x, tid = threadIdx.x;
  const int g = blk / GRPSZ;
  __shared__ ShMem sh;

  // zero-init recurrent state region of ws (re-poisoned each launch)
  for (int i = blk*NT_SCAN + tid; i < WS_STATE_END; i += NB_SCAN*NT_SCAN) A.ws[i] = 0.f;

  // barrier state was zeroed by prenet (stream-ordered). Instance 0 = init sync.
  bar_arrive(g, 0, tid);
  bar_wait(0, tid);

  if (blk < 64)       att_role(A, sh, blk, tid, g);
  else if (blk < 192) dec_role(A, sh, blk, tid, g);
  else if (blk < 224) q_role(A, sh, blk, tid, g);
  else                proj_role(A, sh, blk, tid, g);
}

// ---------------- host ----------------
extern "C" void kernel_launch(void* const* d_in, const int* in_sizes, int n_in,
                              void* d_out, int out_size, void* d_ws, size_t ws_size,
                              hipStream_t stream) {
  const float* memory = (const float*)d_in[0];
  const float* mel    = (const float*)d_in[1];
  const int*   mlen   = (const int*)  d_in[2];
  const float* memp   = (const float*)d_in[3];
  const float* pw1    = (const float*)d_in[4];
  const float* pw2    = (const float*)d_in[5];

  ScanArgs args;
  args.memory = memory; args.memory_pitch = memp; args.mlen = mlen;
  args.att_wih = (const float*)d_in[6];  args.att_whh = (const float*)d_in[7];
  args.att_bih = (const float*)d_in[8];  args.att_bhh = (const float*)d_in[9];
  args.q_w1    = (const float*)d_in[10]; args.q_b1    = (const float*)d_in[11];
  args.q_w2    = (const float*)d_in[12]; args.q_b2    = (const float*)d_in[13];
  args.dec_wih = (const float*)d_in[14]; args.dec_whh = (const float*)d_in[15];
  args.dec_bih = (const float*)d_in[16]; args.dec_bhh = (const float*)d_in[17];
  args.proj_w  = (const float*)d_in[18]; args.proj_b  = (const float*)d_in[19];
  args.out = (float*)d_out; args.ws = (float*)d_ws;

  // jax_threefry_partitionable split: subkey i = threefry(key, (0, i))
  unsigned dk1a, dk1b, dk2a, dk2b;
  threefry2x32(0u, 42u, 0u, 0u, dk1a, dk1b);
  threefry2x32(0u, 42u, 0u, 1u, dk2a, dk2b);

  prenet_kernel<<<dim3(600), dim3(256), 0, stream>>>(mel, pw1, pw2, (float*)d_ws,
                                                     dk1a, dk1b, dk2a, dk2b);

  void* kp[] = { &args };
  hipLaunchCooperativeKernel((void*)scan_kernel, dim3(NB_SCAN), dim3(NT_SCAN),
                             kp, 0, stream);
}

// Round 8
// 31438.354 us; speedup vs baseline: 3.3299x; 1.0548x over previous
//
#include <hip/hip_runtime.h>

// ---------------- constants ----------------
#define NB_SCAN   240
#define NT_SCAN   512
#define TDEC      600
#define ALIGN_OFF 1536000   // 16*1200*80

// ws layout (float offsets) -- 4-deep state buffers
#define WS_ATT_H     0        // [4][16][512]
#define WS_ATT_C     32768    // [16][512]
#define WS_DEC_H     40960    // [4][16][512]
#define WS_DEC_C     73728    // [16][512]
#define WS_CTX       81920    // [4][16][512]
#define WS_CTXP      114688   // [4][16][512]
#define WS_STATE_END 147456
#define WS_PN        163840   // [600][16][256]

// ---------------- per-block generation flags ----------------
// F[blk] = 1 + last completed loop iteration (1 = init done). Monotonic within
// a launch; zeroed by prenet EVERY launch (graph-replay safe). No RMWs.
__device__ unsigned Fdev[256];

// post this block's generation (release: prior stores visible first)
__device__ __forceinline__ void post_flag(int blk, unsigned val, int tid){
  __syncthreads();   // all threads' work + global stores drained (vmcnt 0)
  if (tid == 0)
    __hip_atomic_store(&Fdev[blk], val, __ATOMIC_RELEASE, __HIP_MEMORY_SCOPE_AGENT);
}

// wait per-role thresholds: att F[0..63] >= ta, dec F[64..191] >= td,
// q F[192..223] >= tq, proj F[224..239] >= tp. Values <= 1 are trivially
// satisfied after the init round (all flags >= 1).
__device__ __forceinline__ void wait_flags(int tid, int ta, int td, int tq, int tp){
  int tgt;
  if (tid < 64) tgt = ta;
  else if (tid < 192) tgt = td;
  else if (tid < 224) tgt = tq;
  else if (tid < 240) tgt = tp;
  else tgt = 0;
  if (tgt > 0) {
    while ((int)__hip_atomic_load(&Fdev[tid], __ATOMIC_RELAXED, __HIP_MEMORY_SCOPE_AGENT) < tgt)
      __builtin_amdgcn_s_sleep(1);
  }
  __syncthreads();
  if (tid == 0)
    (void)__hip_atomic_load(&Fdev[0], __ATOMIC_ACQUIRE, __HIP_MEMORY_SCOPE_AGENT);
  __syncthreads();
}

// ---------------- threefry-2x32 (JAX PRNG, partitionable) ----------------
__host__ __device__ inline unsigned rotl_(unsigned x, int n){ return (x<<n)|(x>>(32-n)); }
__host__ __device__ inline void threefry2x32(unsigned k0, unsigned k1,
                                             unsigned x0, unsigned x1,
                                             unsigned &o0, unsigned &o1){
  unsigned ks[3] = {k0, k1, k0 ^ k1 ^ 0x1BD11BDAu};
  x0 += ks[0]; x1 += ks[1];
  const int R0[4] = {13,15,26,6};
  const int R1[4] = {17,29,16,24};
  #pragma unroll
  for (int i = 0; i < 5; ++i) {
    const int* R = (i & 1) ? R1 : R0;
    #pragma unroll
    for (int j = 0; j < 4; ++j) { x0 += x1; x1 = rotl_(x1, R[j]); x1 ^= x0; }
    x0 += ks[(i+1)%3];
    x1 += ks[(i+2)%3] + (unsigned)(i+1);
  }
  o0 = x0; o1 = x1;
}

__device__ __forceinline__ bool keep_mask(unsigned i, unsigned k0, unsigned k1){
  unsigned o0, o1;
  threefry2x32(k0, k1, 0u, i, o0, o1);
  return (((o0 ^ o1) >> 31) == 0u);
}

// ---------------- math helpers ----------------
__device__ __forceinline__ float sigm_(float x){ return 1.f / (1.f + expf(-x)); }
__device__ __forceinline__ float softplus_(float x){ return log1pf(expf(-fabsf(x))) + fmaxf(x, 0.f); }

__device__ __forceinline__ void dot4(float& acc, const float* __restrict__ w,
                                     const float* __restrict__ x, int n){
  const float4* __restrict__ w4 = (const float4*)w;
  const float4* __restrict__ x4 = (const float4*)x;
  const int n4 = n >> 2;
  #pragma unroll 8
  for (int k = 0; k < n4; ++k) {
    float4 a = w4[k], v = x4[k];
    acc = fmaf(a.x, v.x, acc); acc = fmaf(a.y, v.y, acc);
    acc = fmaf(a.z, v.z, acc); acc = fmaf(a.w, v.w, acc);
  }
}

// fully-unrolled in-wave distributed reduce
#define RSTAGE(v, lane, h, cnt) { const bool hi_ = ((lane) & (h)) != 0;      \
  _Pragma("unroll") for (int i_ = 0; i_ < (cnt); ++i_) {                     \
    float s_ = hi_ ? (v)[i_] : (v)[i_+(cnt)];                                \
    float k_ = hi_ ? (v)[i_+(cnt)] : (v)[i_];                                \
    (v)[i_] = k_ + __shfl_xor(s_, (h), 64); } }

// ---------------- prenet (also zeroes flags every launch) ----------
__global__ __launch_bounds__(256) void prenet_kernel(
    const float* __restrict__ mel, const float* __restrict__ w1,
    const float* __restrict__ w2, float* __restrict__ ws,
    unsigned k1a, unsigned k1b, unsigned k2a, unsigned k2b)
{
  __shared__ float in_s[16][84];
  __shared__ float x1_s[16][260];
  const int t = blockIdx.x;
  const int tid = threadIdx.x;

  // reset generation flags for the scan kernel (stream-ordered before it).
  if (t == 0 && tid < 256) Fdev[tid] = 0u;

  for (int i = tid; i < 16*80; i += 256) {
    int b = i / 80, c = i - b*80;
    float v = 0.f;
    if (t > 0) v = mel[((size_t)b*1200 + (2*t-1))*80 + c];
    in_s[b][c] = v;
  }
  __syncthreads();

  const int j2 = tid >> 4, b = tid & 15;

  for (int jo = 0; jo < 16; ++jo) {
    int j = jo*16 + j2;
    float acc = 0.f;
    dot4(acc, w1 + (size_t)j*80, &in_s[b][0], 80);
    acc = fmaxf(acc, 0.f);
    unsigned idx = ((unsigned)t*16u + (unsigned)b)*256u + (unsigned)j;
    acc = keep_mask(idx, k1a, k1b) ? acc*2.f : 0.f;
    x1_s[b][j] = acc;
  }
  __syncthreads();

  for (int jo = 0; jo < 16; ++jo) {
    int j = jo*16 + j2;
    float acc = 0.f;
    dot4(acc, w2 + (size_t)j*256, &x1_s[b][0], 256);
    acc = fmaxf(acc, 0.f);
    unsigned idx = ((unsigned)t*16u + (unsigned)b)*256u + (unsigned)j;
    acc = keep_mask(idx, k2a, k2b) ? acc*2.f : 0.f;
    ws[WS_PN + ((size_t)t*16 + b)*256 + j] = acc;
  }
}

// ---------------- persistent scan kernel ----------------
struct ScanArgs {
  const float* memory; const float* memory_pitch; const int* mlen;
  const float* att_wih; const float* att_whh; const float* att_bih; const float* att_bhh;
  const float* q_w1; const float* q_b1; const float* q_w2; const float* q_b2;
  const float* dec_wih; const float* dec_whh; const float* dec_bih; const float* dec_bhh;
  const float* proj_w; const float* proj_b;
  float* out; float* ws;
};

union ShMem {
  struct { float xs[8][1280]; } att;                       // 40 KB
  struct { float xs[4][2048]; float dbuf[4][64]; } dec;    // 33.8 KB
  struct { float ah[512]; float q1s[256]; float q2s[16];
           float sc[20]; float alpha[600]; float mun[8];
           int iv[4]; } q;                                 // ~5.6 KB
};

// ======== ATT role: blocks 0..63, 8 units each, weights in regs ========
// loop t: wait qF>=t+1 (ctx(t-1), transitively attH(t-1)), decF>=t-1
// (attH 4-buf overwrite guard); work att(t); post t+2.
__device__ __forceinline__ void att_role(const ScanArgs& A, ShMem& sh,
                                         int blk, int tid)
{
  float* ws = A.ws;
  float* attH = ws + WS_ATT_H; float* attC = ws + WS_ATT_C;
  float* ctxB = ws + WS_CTX;
  const float* pn = ws + WS_PN;
  const int lane = tid & 63, wv = tid >> 6;
  const int unit = blk*8 + wv;

  float4 w4[4][5];
  #pragma unroll
  for (int gate = 0; gate < 4; ++gate) {
    int row = gate*512 + unit;
    #pragma unroll
    for (int c = 0; c < 5; ++c) {
      int k = c*256 + lane*4;
      const float* s = (k < 768) ? A.att_wih + (size_t)row*768 + k
                                 : A.att_whh + (size_t)row*512 + (k - 768);
      w4[gate][c] = *(const float4*)s;
    }
  }
  const int brow = (lane >> 4)*512 + unit;
  const float bias = A.att_bih[brow] + A.att_bhh[brow];

  for (int t = 0; t < TDEC; ++t) {
    const int pc = t & 3, pr = (t + 3) & 3;
    wait_flags(tid, 0, t-1, t+1, 0);
    {
      float acc[64];
      #pragma unroll
      for (int i = 0; i < 64; ++i) acc[i] = 0.f;
      #pragma unroll
      for (int bc = 0; bc < 2; ++bc) {
        __syncthreads();
        for (int i = tid; i < 8*320; i += NT_SCAN) {
          int b8 = i / 320, k4 = i - b8*320, kk = k4*4, b = bc*8 + b8;
          float4 v;
          if (kk < 256)      v = *(const float4*)(pn + ((size_t)t*16 + b)*256 + kk);
          else if (kk < 768) v = *(const float4*)(ctxB + pr*8192 + b*512 + (kk-256));
          else               v = *(const float4*)(attH + pr*8192 + b*512 + (kk-768));
          *(float4*)&sh.att.xs[b8][kk] = v;
        }
        __syncthreads();
        #pragma unroll
        for (int b8 = 0; b8 < 8; ++b8) {
          float4 x4[5];
          #pragma unroll
          for (int c = 0; c < 5; ++c) x4[c] = *(const float4*)&sh.att.xs[b8][c*256 + lane*4];
          #pragma unroll
          for (int gate = 0; gate < 4; ++gate) {
            float s = acc[gate*16 + bc*8 + b8];
            #pragma unroll
            for (int c = 0; c < 5; ++c) {
              s = fmaf(w4[gate][c].x, x4[c].x, s); s = fmaf(w4[gate][c].y, x4[c].y, s);
              s = fmaf(w4[gate][c].z, x4[c].z, s); s = fmaf(w4[gate][c].w, x4[c].w, s);
            }
            acc[gate*16 + bc*8 + b8] = s;
          }
        }
      }
      RSTAGE(acc, lane, 32, 32) RSTAGE(acc, lane, 16, 16) RSTAGE(acc, lane, 8, 8)
      RSTAGE(acc, lane, 4, 4)   RSTAGE(acc, lane, 2, 2)   RSTAGE(acc, lane, 1, 1)
      float g0 = acc[0] + bias;
      float gf = __shfl(g0, 16 + (lane & 15), 64);
      float gg = __shfl(g0, 32 + (lane & 15), 64);
      float go = __shfl(g0, 48 + (lane & 15), 64);
      if (lane < 16) {
        int b = lane;
        float c  = attC[b*512 + unit];
        float c2 = sigm_(gf)*c + sigm_(g0)*tanhf(gg);
        float h2 = sigm_(go)*tanhf(c2);
        attC[b*512 + unit] = c2;
        attH[pc*8192 + b*512 + unit] = h2;
      }
    }
    post_flag(blk, t+2, tid);
  }
}

// ======== DEC role: blocks 64..191, 4 units each, K split by wave pair ========
// loop t: wait qF>=t+1 (attH/ctx/ctxp(t-1) transitive), sibling decF>=t+1
// (decH(t-2)), projF>=t-2 (decH slot guard); work dec(t-1); post t+2.
__device__ __forceinline__ void dec_role(const ScanArgs& A, ShMem& sh,
                                         int blk, int tid)
{
  float* ws = A.ws;
  float* attH = ws + WS_ATT_H; float* decH = ws + WS_DEC_H; float* decC = ws + WS_DEC_C;
  float* ctxB = ws + WS_CTX;   float* ctpB = ws + WS_CTXP;
  const int lane = tid & 63, wv = tid >> 6;
  const int db = blk - 64;
  const int unit = db*4 + (wv & 3);
  const int half = wv >> 2, ul = wv & 3;

  float4 w4[4][4];
  #pragma unroll
  for (int gate = 0; gate < 4; ++gate) {
    int row = gate*512 + unit;
    #pragma unroll
    for (int c = 0; c < 4; ++c) {
      int k = half*1024 + c*256 + lane*4;
      const float* s = (k < 1536) ? A.dec_wih + (size_t)row*1536 + k
                                  : A.dec_whh + (size_t)row*512 + (k - 1536);
      w4[gate][c] = *(const float4*)s;
    }
  }
  const int brow = (lane >> 4)*512 + unit;
  const float bias = A.dec_bih[brow] + A.dec_bhh[brow];

  for (int t = 0; t <= TDEC; ++t) {
    const int pr = (t + 3) & 3, pd2 = (t + 2) & 3;
    wait_flags(tid, 0, t+1, t+1, t-2);
    if (t >= 1) {   // dec(t-1): x = [attH(t-1), ctx(t-1), ctxp(t-1), decH(t-2)]
      float acc[64];
      #pragma unroll
      for (int i = 0; i < 64; ++i) acc[i] = 0.f;
      #pragma unroll
      for (int bc = 0; bc < 4; ++bc) {
        __syncthreads();
        for (int i = tid; i < 4*512; i += NT_SCAN) {
          int b4 = i >> 9, k4 = i & 511, kk = k4*4, b = bc*4 + b4;
          float4 v;
          if (kk < 512)       v = *(const float4*)(attH + pr*8192 + b*512 + kk);
          else if (kk < 1024) v = *(const float4*)(ctxB + pr*8192 + b*512 + (kk-512));
          else if (kk < 1536) v = *(const float4*)(ctpB + pr*8192 + b*512 + (kk-1024));
          else                v = *(const float4*)(decH + pd2*8192 + b*512 + (kk-1536));
          *(float4*)&sh.dec.xs[b4][kk] = v;
        }
        __syncthreads();
        #pragma unroll
        for (int b4 = 0; b4 < 4; ++b4) {
          float4 x4[4];
          #pragma unroll
          for (int c = 0; c < 4; ++c) x4[c] = *(const float4*)&sh.dec.xs[b4][half*1024 + c*256 + lane*4];
          #pragma unroll
          for (int gate = 0; gate < 4; ++gate) {
            float s = acc[gate*16 + bc*4 + b4];
            #pragma unroll
            for (int c = 0; c < 4; ++c) {
              s = fmaf(w4[gate][c].x, x4[c].x, s); s = fmaf(w4[gate][c].y, x4[c].y, s);
              s = fmaf(w4[gate][c].z, x4[c].z, s); s = fmaf(w4[gate][c].w, x4[c].w, s);
            }
            acc[gate*16 + bc*4 + b4] = s;
          }
        }
      }
      RSTAGE(acc, lane, 32, 32) RSTAGE(acc, lane, 16, 16) RSTAGE(acc, lane, 8, 8)
      RSTAGE(acc, lane, 4, 4)   RSTAGE(acc, lane, 2, 2)   RSTAGE(acc, lane, 1, 1)
      if (half == 1) sh.dec.dbuf[ul][lane] = acc[0];
      __syncthreads();
      float g0 = acc[0] + sh.dec.dbuf[ul][lane] + bias;   // valid on half==0
      float gf = __shfl(g0, 16 + (lane & 15), 64);
      float gg = __shfl(g0, 32 + (lane & 15), 64);
      float go = __shfl(g0, 48 + (lane & 15), 64);
      if (half == 0 && lane < 16) {
        int b = lane;
        float c  = decC[b*512 + unit];
        float c2 = sigm_(gf)*c + sigm_(g0)*tanhf(gg);
        float h2 = sigm_(go)*tanhf(c2);
        decC[b*512 + unit] = c2;
        decH[pr*8192 + b*512 + unit] = h2;   // decH(t-1)
      }
    }
    post_flag(blk, t+2, tid);
  }
}

// ======== Q role: blocks 192..223 = (b, half), fully self-contained ========
// loop t: wait attF>=t+2 (attH(t)), decF>=t-1, projF>=t-1 (ctx slot guards);
// work q(t); post t+2.
__device__ __forceinline__ void q_role(const ScanArgs& A, ShMem& sh,
                                       int blk, int tid)
{
  float* ws = A.ws;
  float* attH = ws + WS_ATT_H;
  float* ctxB = ws + WS_CTX; float* ctpB = ws + WS_CTXP;
  const int qi = blk - 192, b = qi >> 1, half = qi & 1;
  const int mlen_b = A.mlen[b];

  if (tid < 8) sh.q.mun[tid] = 0.f;   // private mu state (identical in both halves)

  for (int t = 0; t < TDEC; ++t) {
    const int pc = t & 3;
    wait_flags(tid, t+2, t-1, 0, t-1);
    {
      sh.q.ah[tid] = attH[pc*8192 + b*512 + tid];
      __syncthreads();
      { // q1: all 256 rows, row = tid>>1, kq = tid&1 (256-float slice)
        const int row = tid >> 1, kq = tid & 1;
        const float4* wr = (const float4*)(A.q_w1 + (size_t)row*512 + kq*256);
        const float4* xr = (const float4*)&sh.q.ah[kq*256];
        float s0 = 0.f, s1 = 0.f;
        #pragma unroll 8
        for (int j = 0; j < 32; ++j) {
          float4 a = wr[2*j],   v = xr[2*j];
          s0 = fmaf(a.x, v.x, s0); s0 = fmaf(a.y, v.y, s0);
          s0 = fmaf(a.z, v.z, s0); s0 = fmaf(a.w, v.w, s0);
          float4 a2 = wr[2*j+1], v2 = xr[2*j+1];
          s1 = fmaf(a2.x, v2.x, s1); s1 = fmaf(a2.y, v2.y, s1);
          s1 = fmaf(a2.z, v2.z, s1); s1 = fmaf(a2.w, v2.w, s1);
        }
        float s = s0 + s1;
        s += __shfl_xor(s, 1, 64);
        if (kq == 0) sh.q.q1s[row] = tanhf(s + A.q_b1[row]);
      }
      __syncthreads();
      if (tid < 240) {   // q2: 15 rows x 16 lanes x 16-float slice
        const int row = tid >> 4, l16 = tid & 15;
        const float4* wr = (const float4*)(A.q_w2 + (size_t)row*256 + l16*16);
        const float4* xr = (const float4*)&sh.q.q1s[l16*16];
        float s = 0.f;
        #pragma unroll
        for (int j = 0; j < 4; ++j) {
          float4 a = wr[j], v = xr[j];
          s = fmaf(a.x, v.x, s); s = fmaf(a.y, v.y, s);
          s = fmaf(a.z, v.z, s); s = fmaf(a.w, v.w, s);
        }
        s += __shfl_xor(s, 1, 64); s += __shfl_xor(s, 2, 64);
        s += __shfl_xor(s, 4, 64); s += __shfl_xor(s, 8, 64);
        if (l16 == 0) sh.q.q2s[row] = s + A.q_b2[row];
      }
      __syncthreads();
      if (tid == 0) {
        float mx = -1e30f;
        for (int m = 0; m < 5; ++m) mx = fmaxf(mx, sh.q.q2s[m]);
        float ssum = 0.f, e[5];
        for (int m = 0; m < 5; ++m) { e[m] = expf(sh.q.q2s[m]-mx); ssum += e[m]; }
        float mn = 1e30f, mxu = -1e30f;
        for (int m = 0; m < 5; ++m) {
          float wv2 = e[m]/ssum + 1e-6f;
          float sg  = softplus_(sh.q.q2s[5+m]) + 0.5f;
          float is  = 1.f/sg;
          float dl  = softplus_(sh.q.q2s[10+m]);
          float mu  = sh.q.mun[m] + dl;
          sh.q.sc[m] = wv2; sh.q.sc[5+m] = is; sh.q.sc[10+m] = 0.5f*is; sh.q.sc[15+m] = mu;
          sh.q.mun[m] = mu;
          mn = fminf(mn, mu); mxu = fmaxf(mxu, mu);
        }
        int lo = (int)floorf(mn) - 56; if (lo < 0) lo = 0;
        int hi = (int)ceilf(mxu) + 57; if (hi > TDEC) hi = TDEC;
        sh.q.iv[0] = lo; sh.q.iv[1] = hi;
      }
      __syncthreads();
      const int lo = sh.q.iv[0], hi = sh.q.iv[1];
      for (int te = tid; te < TDEC; te += NT_SCAN) {
        float a = 0.f;
        if (te >= lo && te < hi && te < mlen_b) {
          float jj = te + 0.5f;
          #pragma unroll
          for (int m = 0; m < 5; ++m) {
            float zc = (jj - sh.q.sc[15+m]) * sh.q.sc[5+m];
            float hh = sh.q.sc[10+m];
            a += sh.q.sc[m] * (sigm_(zc+hh) - sigm_(zc-hh));
          }
        }
        sh.q.alpha[te] = a;
        if (half == 0)
          A.out[ALIGN_OFF + (size_t)b*360000 + (size_t)t*600 + te] = a;
      }
      __syncthreads();
      {  // ctx: this block's matrix, all 512 dims, 4-way acc split
        const float* mem = half ? A.memory_pitch : A.memory;
        float a0=0.f, a1=0.f, a2=0.f, a3=0.f;
        int te = lo;
        for (; te + 3 < hi; te += 4) {
          const float* mp = mem + ((size_t)b*600 + te)*512 + tid;
          a0 = fmaf(sh.q.alpha[te],   mp[0],    a0);
          a1 = fmaf(sh.q.alpha[te+1], mp[512],  a1);
          a2 = fmaf(sh.q.alpha[te+2], mp[1024], a2);
          a3 = fmaf(sh.q.alpha[te+3], mp[1536], a3);
        }
        for (; te < hi; ++te)
          a0 = fmaf(sh.q.alpha[te], mem[((size_t)b*600 + te)*512 + tid], a0);
        (half ? ctpB : ctxB)[pc*8192 + b*512 + tid] = (a0+a1)+(a2+a3);
      }
    }
    post_flag(blk, t+2, tid);
  }
}

// ======== PROJ role: blocks 224..239, 10 rows each ========
// loop t: wait decF>=t+2 (decH(t-1) written in dec iter t), qF>=t+1
// (ctx/ctxp(t-1)); work proj(t-1); post t+2.
__device__ __forceinline__ void proj_role(const ScanArgs& A, ShMem& sh,
                                          int blk, int tid)
{
  float* ws = A.ws;
  float* decH = ws + WS_DEC_H; float* ctxB = ws + WS_CTX; float* ctpB = ws + WS_CTXP;
  const int lane = tid & 63;
  const bool act = (tid < 320);
  const int row = (blk-224)*10 + (tid >> 5);
  const int l32 = tid & 31;

  float4 w4[12]; float pb = 0.f;
  if (act) {
    #pragma unroll
    for (int c = 0; c < 12; ++c)
      w4[c] = *(const float4*)(A.proj_w + (size_t)row*1536 + c*128 + l32*4);
    pb = A.proj_b[row];
  }

  for (int t = 0; t <= TDEC; ++t) {
    const int pr = (t + 3) & 3;
    wait_flags(tid, 0, t+2, t+1, 0);
    if (t >= 1 && act) {     // proj(t-1): x = [decH(t-1), ctx(t-1), ctxp(t-1)]
      float acc[16];
      #pragma unroll
      for (int i = 0; i < 16; ++i) acc[i] = 0.f;
      #pragma unroll
      for (int b = 0; b < 16; ++b) {
        #pragma unroll
        for (int c = 0; c < 12; ++c) {
          int kk = c*128 + l32*4;
          const float* xp = (kk < 512) ? decH + pr*8192 + b*512 + kk
                          : (kk < 1024) ? ctxB + pr*8192 + b*512 + (kk-512)
                                        : ctpB + pr*8192 + b*512 + (kk-1024);
          float4 v = *(const float4*)xp;
          float s = acc[b];
          s = fmaf(w4[c].x, v.x, s); s = fmaf(w4[c].y, v.y, s);
          s = fmaf(w4[c].z, v.z, s); s = fmaf(w4[c].w, v.w, s);
          acc[b] = s;
        }
      }
      #pragma unroll
      for (int i = 0; i < 16; ++i) acc[i] += __shfl_xor(acc[i], 16, 64);
      RSTAGE(acc, lane, 8, 8) RSTAGE(acc, lane, 4, 4)
      RSTAGE(acc, lane, 2, 2) RSTAGE(acc, lane, 1, 1)
      if ((lane & 31) < 16) {
        int b = lane & 15;
        A.out[(size_t)b*96000 + (size_t)(t-1)*160 + row] = acc[0] + pb;
      }
    }
    post_flag(blk, t+2, tid);
  }
}

__global__ __launch_bounds__(NT_SCAN) void scan_kernel(ScanArgs A)
{
  const int blk = blockIdx.x, tid = threadIdx.x;
  __shared__ ShMem sh;

  // zero-init recurrent state region of ws (re-poisoned each launch)
  for (int i = blk*NT_SCAN + tid; i < WS_STATE_END; i += NB_SCAN*NT_SCAN) A.ws[i] = 0.f;

  // init round: post gen 1, wait all 240 >= 1 (covers ws zeroing)
  post_flag(blk, 1, tid);
  wait_flags(tid, 1, 1, 1, 1);

  if (blk < 64)       att_role(A, sh, blk, tid);
  else if (blk < 192) dec_role(A, sh, blk, tid);
  else if (blk < 224) q_role(A, sh, blk, tid);
  else                proj_role(A, sh, blk, tid);
}

// ---------------- host ----------------
extern "C" void kernel_launch(void* const* d_in, const int* in_sizes, int n_in,
                              void* d_out, int out_size, void* d_ws, size_t ws_size,
                              hipStream_t stream) {
  const float* memory = (const float*)d_in[0];
  const float* mel    = (const float*)d_in[1];
  const int*   mlen   = (const int*)  d_in[2];
  const float* memp   = (const float*)d_in[3];
  const float* pw1    = (const float*)d_in[4];
  const float* pw2    = (const float*)d_in[5];

  ScanArgs args;
  args.memory = memory; args.memory_pitch = memp; args.mlen = mlen;
  args.att_wih = (const float*)d_in[6];  args.att_whh = (const float*)d_in[7];
  args.att_bih = (const float*)d_in[8];  args.att_bhh = (const float*)d_in[9];
  args.q_w1    = (const float*)d_in[10]; args.q_b1    = (const float*)d_in[11];
  args.q_w2    = (const float*)d_in[12]; args.q_b2    = (const float*)d_in[13];
  args.dec_wih = (const float*)d_in[14]; args.dec_whh = (const float*)d_in[15];
  args.dec_bih = (const float*)d_in[16]; args.dec_bhh = (const float*)d_in[17];
  args.proj_w  = (const float*)d_in[18]; args.proj_b  = (const float*)d_in[19];
  args.out = (float*)d_out; args.ws = (float*)d_ws;

  // jax_threefry_partitionable split: subkey i = threefry(key, (0, i))
  unsigned dk1a, dk1b, dk2a, dk2b;
  threefry2x32(0u, 42u, 0u, 0u, dk1a, dk1b);
  threefry2x32(0u, 42u, 0u, 1u, dk2a, dk2b);

  prenet_kernel<<<dim3(600), dim3(256), 0, stream>>>(mel, pw1, pw2, (float*)d_ws,
                                                     dk1a, dk1b, dk2a, dk2b);

  void* kp[] = { &args };
  hipLaunchCooperativeKernel((void*)scan_kernel, dim3(NB_SCAN), dim3(NT_SCAN),
                             kp, 0, stream);
}